// Round 5
// baseline (1123.468 us; speedup 1.0000x reference)
//
#include <hip/hip_runtime.h>

#define TPB 256
#define NB1 256    // stripe blocks for edge passes
#define NBUCK 512  // coarse buckets (dst>>8); supports N <= 131072

using half4_t = __attribute__((ext_vector_type(4))) _Float16;
using half8_t = __attribute__((ext_vector_type(8))) _Float16;
using f32x4 = __attribute__((ext_vector_type(4))) float;

// ---------------- CSR build: atomic-free MSD counting sort ----------------

__global__ __launch_bounds__(256) void hist1_k(const int* __restrict__ ei,
                                               int* __restrict__ hist, int E, int stripe) {
  __shared__ int h[NBUCK];
  for (int i = threadIdx.x; i < NBUCK; i += 256) h[i] = 0;
  __syncthreads();
  int b0 = blockIdx.x * stripe;
  int b1 = min(b0 + stripe, E);
  for (int e = b0 + threadIdx.x; e < b1; e += 256) atomicAdd(&h[ei[E + e] >> 8], 1);
  __syncthreads();
  for (int i = threadIdx.x; i < NBUCK; i += 256) hist[i * NB1 + blockIdx.x] = h[i];
}

__global__ void scan1_k(const int* __restrict__ src, int* __restrict__ out,
                        int* __restrict__ chunk, int n) {
  __shared__ int sh[TPB];
  int i = blockIdx.x * TPB + threadIdx.x;
  int v = (i < n) ? src[i] : 0;
  sh[threadIdx.x] = v;
  __syncthreads();
  for (int off = 1; off < TPB; off <<= 1) {
    int t = (threadIdx.x >= off) ? sh[threadIdx.x - off] : 0;
    __syncthreads();
    sh[threadIdx.x] += t;
    __syncthreads();
  }
  if (i < n) out[i] = sh[threadIdx.x] - v;
  if (threadIdx.x == TPB - 1) chunk[blockIdx.x] = sh[TPB - 1];
}

__global__ void scan2_k(int* __restrict__ chunk, int nb) {
  __shared__ int sh[512];
  int v = (threadIdx.x < nb) ? chunk[threadIdx.x] : 0;
  sh[threadIdx.x] = v;
  __syncthreads();
  for (int off = 1; off < 512; off <<= 1) {
    int t = (threadIdx.x >= off) ? sh[threadIdx.x - off] : 0;
    __syncthreads();
    sh[threadIdx.x] += t;
    __syncthreads();
  }
  if (threadIdx.x < nb) chunk[threadIdx.x] = sh[threadIdx.x] - v;
}

__global__ void scan3_k(int* __restrict__ out, const int* __restrict__ chunk, int n) {
  int i = blockIdx.x * TPB + threadIdx.x;
  if (i < n) out[i] += chunk[blockIdx.x];
}

// pack: src (24 bits) | low8(dst) << 24
__global__ __launch_bounds__(256) void scatter1_k(const int* __restrict__ ei,
                                                  const int* __restrict__ base,
                                                  unsigned* __restrict__ ebuf, int E,
                                                  int stripe) {
  __shared__ int cur[NBUCK];
  for (int i = threadIdx.x; i < NBUCK; i += 256) cur[i] = base[i * NB1 + blockIdx.x];
  __syncthreads();
  int b0 = blockIdx.x * stripe;
  int b1 = min(b0 + stripe, E);
  for (int e = b0 + threadIdx.x; e < b1; e += 256) {
    int s = ei[e];
    int d = ei[E + e];
    int p = atomicAdd(&cur[d >> 8], 1);
    ebuf[p] = (unsigned)s | ((unsigned)(d & 255) << 24);
  }
}

__global__ __launch_bounds__(256) void build_k(const unsigned* __restrict__ ebuf,
                                               const int* __restrict__ base,
                                               int* __restrict__ row_start,
                                               int* __restrict__ deg,
                                               float* __restrict__ invd,
                                               int* __restrict__ csr, int N, int E) {
  __shared__ int h[256];
  __shared__ int excl[256];
  __shared__ int bse[2];
  int b = blockIdx.x;
  int t = threadIdx.x;
  if (t == 0) {
    bse[0] = base[b * NB1];
    bse[1] = (b + 1 < NBUCK) ? base[(b + 1) * NB1] : E;
  }
  h[t] = 0;
  __syncthreads();
  int bs = bse[0], be = bse[1];
  for (int e = bs + t; e < be; e += 256) atomicAdd(&h[ebuf[e] >> 24], 1);
  __syncthreads();
  int v = h[t];
  excl[t] = v;
  __syncthreads();
  for (int off = 1; off < 256; off <<= 1) {
    int tv = (t >= off) ? excl[t - off] : 0;
    __syncthreads();
    excl[t] += tv;
    __syncthreads();
  }
  int ex = excl[t] - v;
  int node = b * 256 + t;
  if (node < N) {
    row_start[node] = bs + ex;
    deg[node] = v;
    invd[node] = 1.0f / fmaxf((float)v, 1.0f);
  }
  h[t] = bs + ex;
  __syncthreads();
  for (int e = bs + t; e < be; e += 256) {
    unsigned p = ebuf[e];
    int pos = atomicAdd(&h[p >> 24], 1);
    csr[pos] = (int)(p & 0xFFFFFFu);
  }
}

// ---------------- fp32 -> fp16 converts ----------------

__global__ void f2h_k(const float* __restrict__ in, _Float16* __restrict__ out, int n4) {
  int i = blockIdx.x * TPB + threadIdx.x;
  if (i < n4) {
    float4 v = ((const float4*)in)[i];
    half4_t o;
    o.x = (_Float16)v.x; o.y = (_Float16)v.y; o.z = (_Float16)v.z; o.w = (_Float16)v.w;
    ((half4_t*)out)[i] = o;
  }
}

// Convert the 6 layer weight matrices (each 128x128) to fp16, packed
// [W1l, W1r, W2l, W2r, W3l, W3r] at 16384-element strides.
__global__ void w6_k(const float* __restrict__ w0, const float* __restrict__ w1,
                     const float* __restrict__ w2, const float* __restrict__ w3,
                     const float* __restrict__ w4, const float* __restrict__ w5,
                     _Float16* __restrict__ out) {
  int t = blockIdx.x * TPB + threadIdx.x;  // t < 6*4096 (float4 units)
  if (t >= 6 * 4096) return;
  int which = t >> 12, i = t & 4095;
  const float* src = which == 0 ? w0 : which == 1 ? w1 : which == 2 ? w2
                   : which == 3 ? w3 : which == 4 ? w4 : w5;
  float4 v = ((const float4*)src)[i];
  half4_t o;
  o.x = (_Float16)v.x; o.y = (_Float16)v.y; o.z = (_Float16)v.z; o.w = (_Float16)v.w;
  ((half4_t*)out)[(size_t)which * 4096 + i] = o;
}

// ---------------- head weight packing (fp16 Wcat, fp32 bcat) ----------------

__global__ void pack_head_k(const float* __restrict__ Wal, const float* __restrict__ War,
                            const float* __restrict__ ba, const float* __restrict__ Wsl,
                            const float* __restrict__ Wsr, const float* __restrict__ bsx,
                            const float* __restrict__ Wel, const float* __restrict__ Wer,
                            const float* __restrict__ be, _Float16* __restrict__ Wcat,
                            float* __restrict__ bcat) {
  int t = blockIdx.x * TPB + threadIdx.x;
  float v = 0.f;
  bool ok = t < 2048;
  if (t < 384) v = Wal[t];
  else if (t < 640) v = Wsl[t - 384];
  else if (t < 1024) v = Wel[t - 640];
  else if (t < 1408) v = War[t - 1024];
  else if (t < 1664) v = Wsr[t - 1408];
  else if (t < 2048) v = Wer[t - 1664];
  if (ok) Wcat[t] = (_Float16)v;
  if (t < 16) {
    float b = 0.f;
    if (t >= 8 && t < 11) b = ba[t - 8];
    else if (t >= 11 && t < 13) b = bsx[t - 11];
    else if (t >= 13) b = be[t - 13];
    bcat[t] = b;
  }
}

// ---------------- fused SAGE layer: wave-autonomous, NO barriers ----------------
// Block = 4 independent waves; each wave owns 4 nodes. No __syncthreads:
// R3's barrier made every block run at max(4 waves' gather).
// Per wave:
//  gather: mean-aggregate 4 nodes (4 rows/instr, prefetch next node's csr
//    chunk) -> wave-private LDS strip A[4][144] (fp16, scaled). Same-wave DS
//    ops execute in order; no barrier needed.
//  GEMM: 16x16x32 f16 MFMA where A rows m read A[m&3] (rows 4..15 duplicates,
//    outputs discarded; 64 MFMAs/tile ~ 3% of the gather wall). 2 column
//    halves (acc[4]) keep VGPR <= 64. C layout: col=lane&15, row=quad*4+reg
//    -> rows 0..3 live in quad-0 lanes.
//  epilogue: quad-0 stages relu(acc+bias) into SEPARATE strip Ot (R4 BUG:
//    staging into A corrupted the ch=1 A-operand reads -> absmax 0.5).
//    mode 0: all lanes read Ot back as half8 for coalesced stores.
//    mode 1: head GEMM reads h3 from Ot vs Wcat.

__global__ __launch_bounds__(256) void fused_sage_k(
    const _Float16* __restrict__ hin, const _Float16* __restrict__ Wh,
    const float* __restrict__ bias, const int* __restrict__ csr,
    const int* __restrict__ row_start, const int* __restrict__ deg,
    const float* __restrict__ invd, _Float16* __restrict__ hout,
    const _Float16* __restrict__ Wcat, const float* __restrict__ bcat,
    float* __restrict__ head_out, int n, int mode) {
  __shared__ _Float16 At[4][4][144];
  __shared__ _Float16 Ot4[4][4][144];
  int wave = threadIdx.x >> 6;
  int lane = threadIdx.x & 63;
  int g = lane >> 4;  // edge slot / quad
  int l = lane & 15;  // feature lane / l16
  _Float16(*A)[144] = At[wave];
  _Float16(*Ot)[144] = Ot4[wave];

  int tb = (blockIdx.x * 4 + wave) * 4;  // this wave's 4-node tile base
  if (tb >= n) return;

  // ---- gather: mean-aggregate 4 nodes into the wave's LDS strip ----
  const _Float16* gbase = hin + (l << 3);
  int rs[4], dg[4];
#pragma unroll
  for (int i = 0; i < 4; ++i) {
    int nd = tb + i;
    bool ok = nd < n;
    rs[i] = ok ? row_start[nd] : 0;
    dg[i] = ok ? deg[nd] : 0;
  }
  int nid[4];
  if (dg[0] >= 16) {
#pragma unroll
    for (int p = 0; p < 4; ++p) nid[p] = csr[rs[0] + 4 * p + g];
  }
  for (int i = 0; i < 4; ++i) {
    int s = rs[i], c = dg[i];
    float a0 = 0.f, a1 = 0.f, a2 = 0.f, a3 = 0.f;
    float a4 = 0.f, a5 = 0.f, a6 = 0.f, a7 = 0.f;
    int j = 0;
    if (c >= 16) {
      int id[4];
#pragma unroll
      for (int p = 0; p < 4; ++p) id[p] = nid[p];
      while (true) {
        half8_t v[4];
#pragma unroll
        for (int p = 0; p < 4; ++p) v[p] = *(const half8_t*)&gbase[(size_t)id[p] * 128];
        j += 16;
        bool more = (j + 16 <= c);
        if (more) {
#pragma unroll
          for (int p = 0; p < 4; ++p) id[p] = csr[s + j + 4 * p + g];
        }
#pragma unroll
        for (int p = 0; p < 4; ++p) {
          a0 += (float)v[p][0]; a1 += (float)v[p][1];
          a2 += (float)v[p][2]; a3 += (float)v[p][3];
          a4 += (float)v[p][4]; a5 += (float)v[p][5];
          a6 += (float)v[p][6]; a7 += (float)v[p][7];
        }
        if (!more) break;
      }
    }
    // prefetch next node's first chunk (hides its idx latency under tail+reduce)
    if (i < 3 && dg[i + 1] >= 16) {
#pragma unroll
      for (int p = 0; p < 4; ++p) nid[p] = csr[rs[i + 1] + 4 * p + g];
    }
    if (j < c) {  // masked tail: 0..15 edges, all loads issued together
      int cm1 = c - 1;
#pragma unroll
      for (int p = 0; p < 4; ++p) {
        int e = j + 4 * p + g;
        float m = (e < c) ? 1.f : 0.f;
        int id = csr[s + min(e, cm1)];
        half8_t v = *(const half8_t*)&gbase[(size_t)id * 128];
        a0 = fmaf(m, (float)v[0], a0); a1 = fmaf(m, (float)v[1], a1);
        a2 = fmaf(m, (float)v[2], a2); a3 = fmaf(m, (float)v[3], a3);
        a4 = fmaf(m, (float)v[4], a4); a5 = fmaf(m, (float)v[5], a5);
        a6 = fmaf(m, (float)v[6], a6); a7 = fmaf(m, (float)v[7], a7);
      }
    }
    // reduce across the 4 edge slots (lanes l, l+16, l+32, l+48)
    a0 += __shfl_xor(a0, 16); a1 += __shfl_xor(a1, 16);
    a2 += __shfl_xor(a2, 16); a3 += __shfl_xor(a3, 16);
    a4 += __shfl_xor(a4, 16); a5 += __shfl_xor(a5, 16);
    a6 += __shfl_xor(a6, 16); a7 += __shfl_xor(a7, 16);
    a0 += __shfl_xor(a0, 32); a1 += __shfl_xor(a1, 32);
    a2 += __shfl_xor(a2, 32); a3 += __shfl_xor(a3, 32);
    a4 += __shfl_xor(a4, 32); a5 += __shfl_xor(a5, 32);
    a6 += __shfl_xor(a6, 32); a7 += __shfl_xor(a7, 32);
    if (g == 0) {
      int node = tb + i;
      float w = (node < n) ? invd[node] : 0.f;
      half8_t r;
      r[0] = (_Float16)(a0 * w); r[1] = (_Float16)(a1 * w);
      r[2] = (_Float16)(a2 * w); r[3] = (_Float16)(a3 * w);
      r[4] = (_Float16)(a4 * w); r[5] = (_Float16)(a5 * w);
      r[6] = (_Float16)(a6 * w); r[7] = (_Float16)(a7 * w);
      *(half8_t*)&A[i][l << 3] = r;
    }
  }
  // no barrier: same-wave LDS writes/reads are in order

  // ---- dual GEMM over 2 column halves (keeps VGPR <= 64) ----
  const _Float16* W2 = Wh + 16384;
  int rrow = tb + (l & 3);
  bool rv = rrow < n;
  size_t rbase = (size_t)rrow * 128 + g * 8;
#pragma unroll
  for (int ch = 0; ch < 2; ++ch) {
    f32x4 acc[4];
#pragma unroll
    for (int ct = 0; ct < 4; ++ct) acc[ct] = (f32x4){0.f, 0.f, 0.f, 0.f};
    // s=0: A = LDS agg rows (row m -> A[m&3]); A is read-only here
#pragma unroll
    for (int kb = 0; kb < 128; kb += 32) {
      half8_t af = *(const half8_t*)&A[l & 3][kb + g * 8];
#pragma unroll
      for (int ct = 0; ct < 4; ++ct) {
        int col = ch * 64 + ct * 16 + l;
        half8_t bf = *(const half8_t*)&Wh[(size_t)col * 128 + kb + g * 8];
        acc[ct] = __builtin_amdgcn_mfma_f32_16x16x32_f16(af, bf, acc[ct], 0, 0, 0);
      }
    }
    // s=1: A = root features (row m -> hin[tb + (m&3)])
#pragma unroll
    for (int kb = 0; kb < 128; kb += 32) {
      half8_t af;
      if (rv) {
        af = *(const half8_t*)&hin[rbase + kb];
      } else {
#pragma unroll
        for (int jj = 0; jj < 8; ++jj) af[jj] = (_Float16)0;
      }
#pragma unroll
      for (int ct = 0; ct < 4; ++ct) {
        int col = ch * 64 + ct * 16 + l;
        half8_t bf = *(const half8_t*)&W2[(size_t)col * 128 + kb + g * 8];
        acc[ct] = __builtin_amdgcn_mfma_f32_16x16x32_f16(af, bf, acc[ct], 0, 0, 0);
      }
    }
    // stage relu(acc + bias) into Ot (rows 0..3 live in quad-0 lanes)
    if (g == 0) {
#pragma unroll
      for (int ct = 0; ct < 4; ++ct) {
        int col = ch * 64 + ct * 16 + l;
        float bc = bias[col];
#pragma unroll
        for (int r = 0; r < 4; ++r) {
          Ot[r][col] = (_Float16)fmaxf(acc[ct][r] + bc, 0.f);
        }
      }
    }
  }

  if (mode == 0) {
    // coalesced store: lane = r*16 + j covers row r, cols j*8..j*8+7
    int rr = lane >> 4, j = lane & 15;
    int orow = tb + rr;
    if (orow < n)
      *(half8_t*)&hout[(size_t)orow * 128 + j * 8] = *(const half8_t*)&Ot[rr][j * 8];
  } else {
    // head GEMM: out16 = h3 @ Wcat^T + bcat (h3 rows in Ot)
    f32x4 ah = (f32x4){0.f, 0.f, 0.f, 0.f};
#pragma unroll
    for (int kb = 0; kb < 128; kb += 32) {
      half8_t af = *(const half8_t*)&Ot[l & 3][kb + g * 8];
      half8_t bf = *(const half8_t*)&Wcat[(size_t)l * 128 + kb + g * 8];
      ah = __builtin_amdgcn_mfma_f32_16x16x32_f16(af, bf, ah, 0, 0, 0);
    }
    if (g == 0) {
      float bc = bcat[l];
#pragma unroll
      for (int r = 0; r < 4; ++r) {
        int orow = tb + r;
        if (orow < n) head_out[(size_t)orow * 16 + l] = ah[r] + bc;
      }
    }
  }
}

// ---------------- 8-dim aggregation + output write ----------------
// out layout: age [n,3] @0, sex [n,2] @3n, eth [n,3] @5n
// Lane layout: g = lane>>2 picks one of 16 edge slots; c2 = lane&3 covers
// features 2*c2, 2*c2+1 via float2 loads. One instruction gathers 16 rows;
// main loop keeps 2 (32 edges) in flight. Branch-free masked tail.

__global__ void agg8_k(const float* __restrict__ hlr, const int* __restrict__ csr,
                       const int* __restrict__ row_start, const int* __restrict__ deg,
                       const float* __restrict__ invd, float* __restrict__ out, int n) {
  int node = (blockIdx.x << 2) + (threadIdx.x >> 6);
  if (node >= n) return;
  int lane = threadIdx.x & 63;
  int c2 = lane & 3;  // feature pair
  int g = lane >> 2;  // edge slot 0..15
  int s = row_start[node], cnt = deg[node];
  float ax = 0.f, ay = 0.f;
  int j = 0;
  for (; j + 32 <= cnt; j += 32) {
#pragma unroll
    for (int p = 0; p < 2; ++p) {
      int id = csr[s + j + 16 * p + g];
      float2 v = *(const float2*)&hlr[(size_t)id * 16 + 2 * c2];
      ax += v.x;
      ay += v.y;
    }
  }
  if (j < cnt) {
    int cm1 = cnt - 1;
#pragma unroll
    for (int p = 0; p < 2; ++p) {
      int e = j + 16 * p + g;
      float m = (e < cnt) ? 1.f : 0.f;
      int id = csr[s + min(e, cm1)];
      float2 v = *(const float2*)&hlr[(size_t)id * 16 + 2 * c2];
      ax = fmaf(m, v.x, ax);
      ay = fmaf(m, v.y, ay);
    }
  }
  ax += __shfl_xor(ax, 4);  ay += __shfl_xor(ay, 4);
  ax += __shfl_xor(ax, 8);  ay += __shfl_xor(ay, 8);
  ax += __shfl_xor(ax, 16); ay += __shfl_xor(ay, 16);
  ax += __shfl_xor(ax, 32); ay += __shfl_xor(ay, 32);
  if (g == 0) {
    float w = invd[node];
    float r0 = ax * w + hlr[(size_t)node * 16 + 8 + 2 * c2];
    float r1 = ay * w + hlr[(size_t)node * 16 + 8 + 2 * c2 + 1];
    float rr[2] = {r0, r1};
#pragma unroll
    for (int q = 0; q < 2; ++q) {
      int f = 2 * c2 + q;
      float r = rr[q];
      if (f < 3) out[(size_t)node * 3 + f] = r;
      else if (f < 5) out[(size_t)3 * n + (size_t)node * 2 + (f - 3)] = r;
      else out[(size_t)5 * n + (size_t)node * 3 + (f - 5)] = r;
    }
  }
}

// ---------------- launch ----------------

extern "C" void kernel_launch(void* const* d_in, const int* in_sizes, int n_in,
                              void* d_out, int out_size, void* d_ws, size_t ws_size,
                              hipStream_t stream) {
  const float* x = (const float*)d_in[0];
  const int* ei = (const int*)d_in[1];
  const float* W1l = (const float*)d_in[2];
  const float* W1r = (const float*)d_in[3];
  const float* b1 = (const float*)d_in[4];
  const float* W2l = (const float*)d_in[5];
  const float* W2r = (const float*)d_in[6];
  const float* b2 = (const float*)d_in[7];
  const float* W3l = (const float*)d_in[8];
  const float* W3r = (const float*)d_in[9];
  const float* b3 = (const float*)d_in[10];
  const float* Wal = (const float*)d_in[11];
  const float* War = (const float*)d_in[12];
  const float* ba = (const float*)d_in[13];
  const float* Wsl = (const float*)d_in[14];
  const float* Wsr = (const float*)d_in[15];
  const float* bsx = (const float*)d_in[16];
  const float* Wel = (const float*)d_in[17];
  const float* Wer = (const float*)d_in[18];
  const float* be = (const float*)d_in[19];

  int N = in_sizes[0] / 128;
  int E = in_sizes[1] / 2;
  int NBKT = (N + 255) >> 8;

  char* w = (char*)d_ws;
  auto alloc = [&](size_t b) {
    char* p = w;
    w += (b + 255) & ~(size_t)255;
    return p;
  };
  int* deg = (int*)alloc((size_t)N * 4);
  int* row_start = (int*)alloc((size_t)N * 4);
  float* invd = (float*)alloc((size_t)N * 4);
  int* hist = (int*)alloc((size_t)NBUCK * NB1 * 4);
  int* chunk = (int*)alloc(512 * 4);
  int* csr = (int*)alloc((size_t)E * 4);
  // xh (fp16 x, N*128*2 B) aliases ebuf (E*4 B): ebuf dead after build_k.
  size_t xh_bytes = (size_t)N * 128 * 2;
  size_t ebuf_bytes = (size_t)E * 4;
  char* region = (char*)alloc(xh_bytes > ebuf_bytes ? xh_bytes : ebuf_bytes);
  unsigned* ebuf = (unsigned*)region;
  _Float16* xh = (_Float16*)region;
  _Float16* hA = (_Float16*)alloc((size_t)N * 128 * 2);
  _Float16* hB = (_Float16*)alloc((size_t)N * 128 * 2);
  _Float16* wh = (_Float16*)alloc((size_t)6 * 16384 * 2);
  _Float16* Wcat = (_Float16*)alloc(2048 * 2);
  float* bcat = (float*)alloc(16 * 4);
  float* head_lr = (float*)alloc((size_t)N * 16 * 4);

  int stripe = (((E + NB1 - 1) / NB1) + 255) & ~255;
  int nscan = NBUCK * NB1;
  int nbScan = (nscan + TPB - 1) / TPB;
  int nbNode = (N + 3) / 4;
  int nbM = (N + 15) / 16;  // 16 nodes per block (4 waves x 4 nodes, no barrier)
  int nbC = (N * 32 + TPB - 1) / TPB;

  // CSR build — no global atomics
  hist1_k<<<NB1, 256, 0, stream>>>(ei, hist, E, stripe);
  scan1_k<<<nbScan, TPB, 0, stream>>>(hist, hist, chunk, nscan);
  scan2_k<<<1, 512, 0, stream>>>(chunk, nbScan);
  scan3_k<<<nbScan, TPB, 0, stream>>>(hist, chunk, nscan);
  scatter1_k<<<NB1, 256, 0, stream>>>(ei, hist, ebuf, E, stripe);
  build_k<<<NBKT, 256, 0, stream>>>(ebuf, hist, row_start, deg, invd, csr, N, E);

  // fp16 conversions (xh aliases ebuf: must come after build_k)
  f2h_k<<<nbC, TPB, 0, stream>>>(x, xh, N * 32);
  w6_k<<<96, TPB, 0, stream>>>(W1l, W1r, W2l, W2r, W3l, W3r, wh);
  pack_head_k<<<8, TPB, 0, stream>>>(Wal, War, ba, Wsl, Wsr, bsx, Wel, Wer, be, Wcat, bcat);

  // layer 1: x -> hA
  fused_sage_k<<<nbM, TPB, 0, stream>>>(xh, wh + 0 * 16384, b1, csr, row_start, deg,
                                        invd, hA, nullptr, nullptr, nullptr, N, 0);
  // layer 2: hA -> hB
  fused_sage_k<<<nbM, TPB, 0, stream>>>(hA, wh + 2 * 16384, b2, csr, row_start, deg,
                                        invd, hB, nullptr, nullptr, nullptr, N, 0);
  // layer 3 + heads: hB -> head_lr[n,16]
  fused_sage_k<<<nbM, TPB, 0, stream>>>(hB, wh + 4 * 16384, b3, csr, row_start, deg,
                                        invd, nullptr, Wcat, bcat, head_lr, N, 1);
  // final 8-dim neighbor aggregation + output
  agg8_k<<<nbNode, TPB, 0, stream>>>(head_lr, csr, row_start, deg, invd, (float*)d_out, N);
}

// Round 6
// 767.147 us; speedup vs baseline: 1.4645x; 1.4645x over previous
//
#include <hip/hip_runtime.h>

#define TPB 256
#define NB1 256    // stripe blocks for edge passes
#define NBUCK 512  // coarse buckets (dst>>8); supports N <= 131072

using half4_t = __attribute__((ext_vector_type(4))) _Float16;
using half8_t = __attribute__((ext_vector_type(8))) _Float16;
using f32x4 = __attribute__((ext_vector_type(4))) float;

// ---------------- CSR build: atomic-free MSD counting sort ----------------

__global__ __launch_bounds__(256) void hist1_k(const int* __restrict__ ei,
                                               int* __restrict__ hist, int E, int stripe) {
  __shared__ int h[NBUCK];
  for (int i = threadIdx.x; i < NBUCK; i += 256) h[i] = 0;
  __syncthreads();
  int b0 = blockIdx.x * stripe;
  int b1 = min(b0 + stripe, E);
  for (int e = b0 + threadIdx.x; e < b1; e += 256) atomicAdd(&h[ei[E + e] >> 8], 1);
  __syncthreads();
  for (int i = threadIdx.x; i < NBUCK; i += 256) hist[i * NB1 + blockIdx.x] = h[i];
}

__global__ void scan1_k(const int* __restrict__ src, int* __restrict__ out,
                        int* __restrict__ chunk, int n) {
  __shared__ int sh[TPB];
  int i = blockIdx.x * TPB + threadIdx.x;
  int v = (i < n) ? src[i] : 0;
  sh[threadIdx.x] = v;
  __syncthreads();
  for (int off = 1; off < TPB; off <<= 1) {
    int t = (threadIdx.x >= off) ? sh[threadIdx.x - off] : 0;
    __syncthreads();
    sh[threadIdx.x] += t;
    __syncthreads();
  }
  if (i < n) out[i] = sh[threadIdx.x] - v;
  if (threadIdx.x == TPB - 1) chunk[blockIdx.x] = sh[TPB - 1];
}

__global__ void scan2_k(int* __restrict__ chunk, int nb) {
  __shared__ int sh[512];
  int v = (threadIdx.x < nb) ? chunk[threadIdx.x] : 0;
  sh[threadIdx.x] = v;
  __syncthreads();
  for (int off = 1; off < 512; off <<= 1) {
    int t = (threadIdx.x >= off) ? sh[threadIdx.x - off] : 0;
    __syncthreads();
    sh[threadIdx.x] += t;
    __syncthreads();
  }
  if (threadIdx.x < nb) chunk[threadIdx.x] = sh[threadIdx.x] - v;
}

__global__ void scan3_k(int* __restrict__ out, const int* __restrict__ chunk, int n) {
  int i = blockIdx.x * TPB + threadIdx.x;
  if (i < n) out[i] += chunk[blockIdx.x];
}

// pack: src (24 bits) | low8(dst) << 24
__global__ __launch_bounds__(256) void scatter1_k(const int* __restrict__ ei,
                                                  const int* __restrict__ base,
                                                  unsigned* __restrict__ ebuf, int E,
                                                  int stripe) {
  __shared__ int cur[NBUCK];
  for (int i = threadIdx.x; i < NBUCK; i += 256) cur[i] = base[i * NB1 + blockIdx.x];
  __syncthreads();
  int b0 = blockIdx.x * stripe;
  int b1 = min(b0 + stripe, E);
  for (int e = b0 + threadIdx.x; e < b1; e += 256) {
    int s = ei[e];
    int d = ei[E + e];
    int p = atomicAdd(&cur[d >> 8], 1);
    ebuf[p] = (unsigned)s | ((unsigned)(d & 255) << 24);
  }
}

__global__ __launch_bounds__(256) void build_k(const unsigned* __restrict__ ebuf,
                                               const int* __restrict__ base,
                                               int* __restrict__ row_start,
                                               int* __restrict__ deg,
                                               float* __restrict__ invd,
                                               int* __restrict__ csr, int N, int E) {
  __shared__ int h[256];
  __shared__ int excl[256];
  __shared__ int bse[2];
  int b = blockIdx.x;
  int t = threadIdx.x;
  if (t == 0) {
    bse[0] = base[b * NB1];
    bse[1] = (b + 1 < NBUCK) ? base[(b + 1) * NB1] : E;
  }
  h[t] = 0;
  __syncthreads();
  int bs = bse[0], be = bse[1];
  for (int e = bs + t; e < be; e += 256) atomicAdd(&h[ebuf[e] >> 24], 1);
  __syncthreads();
  int v = h[t];
  excl[t] = v;
  __syncthreads();
  for (int off = 1; off < 256; off <<= 1) {
    int tv = (t >= off) ? excl[t - off] : 0;
    __syncthreads();
    excl[t] += tv;
    __syncthreads();
  }
  int ex = excl[t] - v;
  int node = b * 256 + t;
  if (node < N) {
    row_start[node] = bs + ex;
    deg[node] = v;
    invd[node] = 1.0f / fmaxf((float)v, 1.0f);
  }
  h[t] = bs + ex;
  __syncthreads();
  for (int e = bs + t; e < be; e += 256) {
    unsigned p = ebuf[e];
    int pos = atomicAdd(&h[p >> 24], 1);
    csr[pos] = (int)(p & 0xFFFFFFu);
  }
}

// ---------------- prep: f2h(x) + weight converts + head pack + counter zero ----------------
// Merged from 3 kernels: fewer launches. Also zeroes the persistent-tile
// counters every replay (runs before the layer kernels in-stream).

__global__ void prep_k(const float* __restrict__ x, _Float16* __restrict__ xh, int n4,
                       const float* __restrict__ w0, const float* __restrict__ w1,
                       const float* __restrict__ w2, const float* __restrict__ w3,
                       const float* __restrict__ w4, const float* __restrict__ w5,
                       _Float16* __restrict__ wh,
                       const float* __restrict__ Wal, const float* __restrict__ War,
                       const float* __restrict__ ba, const float* __restrict__ Wsl,
                       const float* __restrict__ Wsr, const float* __restrict__ bsx,
                       const float* __restrict__ Wel, const float* __restrict__ Wer,
                       const float* __restrict__ be, _Float16* __restrict__ Wcat,
                       float* __restrict__ bcat, int* __restrict__ ctrs) {
  int t = blockIdx.x * TPB + threadIdx.x;
  if (t < n4) {
    float4 v = ((const float4*)x)[t];
    half4_t o;
    o.x = (_Float16)v.x; o.y = (_Float16)v.y; o.z = (_Float16)v.z; o.w = (_Float16)v.w;
    ((half4_t*)xh)[t] = o;
  }
  if (t < 6 * 4096) {
    int which = t >> 12, i = t & 4095;
    const float* src = which == 0 ? w0 : which == 1 ? w1 : which == 2 ? w2
                     : which == 3 ? w3 : which == 4 ? w4 : w5;
    float4 v = ((const float4*)src)[i];
    half4_t o;
    o.x = (_Float16)v.x; o.y = (_Float16)v.y; o.z = (_Float16)v.z; o.w = (_Float16)v.w;
    ((half4_t*)wh)[(size_t)which * 4096 + i] = o;
  }
  if (t < 2048) {
    float v = 0.f;
    if (t < 384) v = Wal[t];
    else if (t < 640) v = Wsl[t - 384];
    else if (t < 1024) v = Wel[t - 640];
    else if (t < 1408) v = War[t - 1024];
    else if (t < 1664) v = Wsr[t - 1408];
    else v = Wer[t - 1664];
    Wcat[t] = (_Float16)v;
  }
  if (t < 16) {
    float b = 0.f;
    if (t >= 8 && t < 11) b = ba[t - 8];
    else if (t >= 11 && t < 13) b = bsx[t - 11];
    else if (t >= 13) b = be[t - 13];
    bcat[t] = b;
  }
  if (t < 4) ctrs[t] = 0;
}

// ---------------- fused SAGE layer: persistent blocks, R3 tile structure ----------------
// R5 lesson: wave-autonomous 4-row GEMM tiles cost 4x MFMA + 4x weight traffic
// (300us). R3's shared 16-node tile (each wave 1/4 of the columns, zero
// redundant MFMA) is correct; its loss was the drain tail (25k waves = 3.05
// residency rounds -> ~1/3 of dispatch draining, occupancy 53%).
// Fix: persistent grid of 2048 blocks pulling 16-node tiles off a global
// atomic counter. Last-round spread ~ one tile; degree variance load-balances.
// Per tile (R3 code): 4 waves gather 4 nodes each -> LDS At[16][144];
// barrier; dual GEMM, wave w covers cols 32w..32w+31; mode 0 relu-store,
// mode 1 stages h3 in At then wave0 head-GEMM vs Wcat, split outputs:
//   head_g[n][8] = gathered part (32 B rows for agg8), head_r[n][8] = root.

__global__ __launch_bounds__(256) void fused_sage_k(
    const _Float16* __restrict__ hin, const _Float16* __restrict__ Wh,
    const float* __restrict__ bias, const int* __restrict__ csr,
    const int* __restrict__ row_start, const int* __restrict__ deg,
    const float* __restrict__ invd, _Float16* __restrict__ hout,
    const _Float16* __restrict__ Wcat, const float* __restrict__ bcat,
    float* __restrict__ head_g, float* __restrict__ head_r,
    int* __restrict__ ctr, int ntiles, int n, int mode) {
  __shared__ _Float16 At[16][144];
  __shared__ int tile_s;
  int wave = threadIdx.x >> 6;
  int lane = threadIdx.x & 63;
  int g = lane >> 4;  // edge slot / quad
  int l = lane & 15;  // feature lane / l16
  const _Float16* gbase = hin + (l << 3);
  const _Float16* W2 = Wh + 16384;

  for (;;) {
    if (threadIdx.x == 0) tile_s = atomicAdd(ctr, 1);
    __syncthreads();  // publish tile; also protects At from prev tile's GEMM reads
    int tile = tile_s;
    if (tile >= ntiles) break;
    int ms = tile * 16;

    // ---- phase 1: mean-aggregate 4 nodes per wave into LDS ----
    int nb = ms + wave * 4;
    int rs[4], dg[4];
#pragma unroll
    for (int i = 0; i < 4; ++i) {
      int nd = nb + i;
      bool ok = nd < n;
      rs[i] = ok ? row_start[nd] : 0;
      dg[i] = ok ? deg[nd] : 0;
    }
    int nid[4];
    if (dg[0] >= 16) {
#pragma unroll
      for (int p = 0; p < 4; ++p) nid[p] = csr[rs[0] + 4 * p + g];
    }
    for (int i = 0; i < 4; ++i) {
      int s = rs[i], c = dg[i];
      float a0 = 0.f, a1 = 0.f, a2 = 0.f, a3 = 0.f;
      float a4 = 0.f, a5 = 0.f, a6 = 0.f, a7 = 0.f;
      int j = 0;
      if (c >= 16) {
        int id[4];
#pragma unroll
        for (int p = 0; p < 4; ++p) id[p] = nid[p];
        while (true) {
          half8_t v[4];
#pragma unroll
          for (int p = 0; p < 4; ++p) v[p] = *(const half8_t*)&gbase[(size_t)id[p] * 128];
          j += 16;
          bool more = (j + 16 <= c);
          if (more) {
#pragma unroll
            for (int p = 0; p < 4; ++p) id[p] = csr[s + j + 4 * p + g];
          }
#pragma unroll
          for (int p = 0; p < 4; ++p) {
            a0 += (float)v[p][0]; a1 += (float)v[p][1];
            a2 += (float)v[p][2]; a3 += (float)v[p][3];
            a4 += (float)v[p][4]; a5 += (float)v[p][5];
            a6 += (float)v[p][6]; a7 += (float)v[p][7];
          }
          if (!more) break;
        }
      }
      // prefetch next node's first chunk (hides idx latency under tail+reduce)
      if (i < 3 && dg[i + 1] >= 16) {
#pragma unroll
        for (int p = 0; p < 4; ++p) nid[p] = csr[rs[i + 1] + 4 * p + g];
      }
      if (j < c) {  // masked tail: 0..15 edges, all loads issued together
        int cm1 = c - 1;
#pragma unroll
        for (int p = 0; p < 4; ++p) {
          int e = j + 4 * p + g;
          float m = (e < c) ? 1.f : 0.f;
          int id = csr[s + min(e, cm1)];
          half8_t v = *(const half8_t*)&gbase[(size_t)id * 128];
          a0 = fmaf(m, (float)v[0], a0); a1 = fmaf(m, (float)v[1], a1);
          a2 = fmaf(m, (float)v[2], a2); a3 = fmaf(m, (float)v[3], a3);
          a4 = fmaf(m, (float)v[4], a4); a5 = fmaf(m, (float)v[5], a5);
          a6 = fmaf(m, (float)v[6], a6); a7 = fmaf(m, (float)v[7], a7);
        }
      }
      // reduce across the 4 edge slots (lanes l, l+16, l+32, l+48)
      a0 += __shfl_xor(a0, 16); a1 += __shfl_xor(a1, 16);
      a2 += __shfl_xor(a2, 16); a3 += __shfl_xor(a3, 16);
      a4 += __shfl_xor(a4, 16); a5 += __shfl_xor(a5, 16);
      a6 += __shfl_xor(a6, 16); a7 += __shfl_xor(a7, 16);
      a0 += __shfl_xor(a0, 32); a1 += __shfl_xor(a1, 32);
      a2 += __shfl_xor(a2, 32); a3 += __shfl_xor(a3, 32);
      a4 += __shfl_xor(a4, 32); a5 += __shfl_xor(a5, 32);
      a6 += __shfl_xor(a6, 32); a7 += __shfl_xor(a7, 32);
      if (g == 0) {
        int node = nb + i;
        float w = (node < n) ? invd[node] : 0.f;
        half8_t r;
        r[0] = (_Float16)(a0 * w); r[1] = (_Float16)(a1 * w);
        r[2] = (_Float16)(a2 * w); r[3] = (_Float16)(a3 * w);
        r[4] = (_Float16)(a4 * w); r[5] = (_Float16)(a5 * w);
        r[6] = (_Float16)(a6 * w); r[7] = (_Float16)(a7 * w);
        *(half8_t*)&At[wave * 4 + i][l << 3] = r;
      }
    }
    __syncthreads();

    // ---- phase 2: dual GEMM; wave covers cols wave*32..wave*32+31 ----
    int arow = ms + l;
    bool valid = arow < n;
    f32x4 acc[2];
    acc[0] = (f32x4){0.f, 0.f, 0.f, 0.f};
    acc[1] = (f32x4){0.f, 0.f, 0.f, 0.f};

    // s=0: A = LDS agg tile
#pragma unroll
    for (int kb = 0; kb < 128; kb += 32) {
      half8_t af = *(const half8_t*)&At[l][kb + g * 8];
#pragma unroll
      for (int ct = 0; ct < 2; ++ct) {
        int ocol = wave * 32 + ct * 16 + l;
        half8_t bf = *(const half8_t*)&Wh[(size_t)ocol * 128 + kb + g * 8];
        acc[ct] = __builtin_amdgcn_mfma_f32_16x16x32_f16(af, bf, acc[ct], 0, 0, 0);
      }
    }
    // s=1: A = root features from global
    {
      size_t abase = (size_t)arow * 128 + g * 8;
#pragma unroll
      for (int kb = 0; kb < 128; kb += 32) {
        half8_t af;
        if (valid) {
          af = *(const half8_t*)&hin[abase + kb];
        } else {
#pragma unroll
          for (int jj = 0; jj < 8; ++jj) af[jj] = (_Float16)0;
        }
#pragma unroll
        for (int ct = 0; ct < 2; ++ct) {
          int ocol = wave * 32 + ct * 16 + l;
          half8_t bf = *(const half8_t*)&W2[(size_t)ocol * 128 + kb + g * 8];
          acc[ct] = __builtin_amdgcn_mfma_f32_16x16x32_f16(af, bf, acc[ct], 0, 0, 0);
        }
      }
    }

    if (mode == 0) {
#pragma unroll
      for (int ct = 0; ct < 2; ++ct) {
        int col = wave * 32 + ct * 16 + l;
        float bcol = bias[col];
#pragma unroll
        for (int r = 0; r < 4; ++r) {
          int row = ms + g * 4 + r;
          if (row < n) {
            float v = fmaxf(acc[ct][r] + bcol, 0.f);
            hout[(size_t)row * 128 + col] = (_Float16)v;
          }
        }
      }
    } else {
      // h3 = relu(acc + bias) -> LDS, then head GEMM vs Wcat (wave 0 only)
      __syncthreads();
#pragma unroll
      for (int ct = 0; ct < 2; ++ct) {
        int col = wave * 32 + ct * 16 + l;
        float bcol = bias[col];
#pragma unroll
        for (int r = 0; r < 4; ++r) {
          float v = fmaxf(acc[ct][r] + bcol, 0.f);
          At[g * 4 + r][col] = (_Float16)v;
        }
      }
      __syncthreads();
      if (wave == 0) {
        f32x4 ah = (f32x4){0.f, 0.f, 0.f, 0.f};
#pragma unroll
        for (int kb = 0; kb < 128; kb += 32) {
          half8_t af = *(const half8_t*)&At[l][kb + g * 8];
          half8_t bf = *(const half8_t*)&Wcat[(size_t)l * 128 + kb + g * 8];
          ah = __builtin_amdgcn_mfma_f32_16x16x32_f16(af, bf, ah, 0, 0, 0);
        }
        float bc = bcat[l];
#pragma unroll
        for (int r = 0; r < 4; ++r) {
          int orow = ms + g * 4 + r;
          if (orow < n) {
            float v = ah[r] + bc;
            if (l < 8) head_g[(size_t)orow * 8 + l] = v;
            else head_r[(size_t)orow * 8 + (l - 8)] = v;
          }
        }
      }
    }
  }
}

// ---------------- 8-dim aggregation + output write ----------------
// out layout: age [n,3] @0, sex [n,2] @3n, eth [n,3] @5n
// head_g rows are 32 B (8 floats): half the random-gather line traffic of the
// old [n,16] layout. Root part comes from head_r (coalesced-ish 32 B rows).

__global__ void agg8_k(const float* __restrict__ head_g, const float* __restrict__ head_r,
                       const int* __restrict__ csr, const int* __restrict__ row_start,
                       const int* __restrict__ deg, const float* __restrict__ invd,
                       float* __restrict__ out, int n) {
  int node = (blockIdx.x << 2) + (threadIdx.x >> 6);
  if (node >= n) return;
  int lane = threadIdx.x & 63;
  int c2 = lane & 3;  // feature pair
  int g = lane >> 2;  // edge slot 0..15
  int s = row_start[node], cnt = deg[node];
  float ax = 0.f, ay = 0.f;
  int j = 0;
  for (; j + 32 <= cnt; j += 32) {
#pragma unroll
    for (int p = 0; p < 2; ++p) {
      int id = csr[s + j + 16 * p + g];
      float2 v = *(const float2*)&head_g[(size_t)id * 8 + 2 * c2];
      ax += v.x;
      ay += v.y;
    }
  }
  if (j < cnt) {
    int cm1 = cnt - 1;
#pragma unroll
    for (int p = 0; p < 2; ++p) {
      int e = j + 16 * p + g;
      float m = (e < cnt) ? 1.f : 0.f;
      int id = csr[s + min(e, cm1)];
      float2 v = *(const float2*)&head_g[(size_t)id * 8 + 2 * c2];
      ax = fmaf(m, v.x, ax);
      ay = fmaf(m, v.y, ay);
    }
  }
  ax += __shfl_xor(ax, 4);  ay += __shfl_xor(ay, 4);
  ax += __shfl_xor(ax, 8);  ay += __shfl_xor(ay, 8);
  ax += __shfl_xor(ax, 16); ay += __shfl_xor(ay, 16);
  ax += __shfl_xor(ax, 32); ay += __shfl_xor(ay, 32);
  if (g == 0) {
    float w = invd[node];
    float r0 = ax * w + head_r[(size_t)node * 8 + 2 * c2];
    float r1 = ay * w + head_r[(size_t)node * 8 + 2 * c2 + 1];
    float rr[2] = {r0, r1};
#pragma unroll
    for (int q = 0; q < 2; ++q) {
      int f = 2 * c2 + q;
      float r = rr[q];
      if (f < 3) out[(size_t)node * 3 + f] = r;
      else if (f < 5) out[(size_t)3 * n + (size_t)node * 2 + (f - 3)] = r;
      else out[(size_t)5 * n + (size_t)node * 3 + (f - 5)] = r;
    }
  }
}

// ---------------- launch ----------------

extern "C" void kernel_launch(void* const* d_in, const int* in_sizes, int n_in,
                              void* d_out, int out_size, void* d_ws, size_t ws_size,
                              hipStream_t stream) {
  const float* x = (const float*)d_in[0];
  const int* ei = (const int*)d_in[1];
  const float* W1l = (const float*)d_in[2];
  const float* W1r = (const float*)d_in[3];
  const float* b1 = (const float*)d_in[4];
  const float* W2l = (const float*)d_in[5];
  const float* W2r = (const float*)d_in[6];
  const float* b2 = (const float*)d_in[7];
  const float* W3l = (const float*)d_in[8];
  const float* W3r = (const float*)d_in[9];
  const float* b3 = (const float*)d_in[10];
  const float* Wal = (const float*)d_in[11];
  const float* War = (const float*)d_in[12];
  const float* ba = (const float*)d_in[13];
  const float* Wsl = (const float*)d_in[14];
  const float* Wsr = (const float*)d_in[15];
  const float* bsx = (const float*)d_in[16];
  const float* Wel = (const float*)d_in[17];
  const float* Wer = (const float*)d_in[18];
  const float* be = (const float*)d_in[19];

  int N = in_sizes[0] / 128;
  int E = in_sizes[1] / 2;
  int NBKT = (N + 255) >> 8;

  char* w = (char*)d_ws;
  auto alloc = [&](size_t b) {
    char* p = w;
    w += (b + 255) & ~(size_t)255;
    return p;
  };
  int* deg = (int*)alloc((size_t)N * 4);
  int* row_start = (int*)alloc((size_t)N * 4);
  float* invd = (float*)alloc((size_t)N * 4);
  int* hist = (int*)alloc((size_t)NBUCK * NB1 * 4);
  int* chunk = (int*)alloc(512 * 4);
  int* csr = (int*)alloc((size_t)E * 4);
  // xh (fp16 x, N*128*2 B) aliases ebuf (E*4 B): ebuf dead after build_k.
  size_t xh_bytes = (size_t)N * 128 * 2;
  size_t ebuf_bytes = (size_t)E * 4;
  char* region = (char*)alloc(xh_bytes > ebuf_bytes ? xh_bytes : ebuf_bytes);
  unsigned* ebuf = (unsigned*)region;
  _Float16* xh = (_Float16*)region;
  _Float16* hA = (_Float16*)alloc((size_t)N * 128 * 2);
  _Float16* hB = (_Float16*)alloc((size_t)N * 128 * 2);
  _Float16* wh = (_Float16*)alloc((size_t)6 * 16384 * 2);
  _Float16* Wcat = (_Float16*)alloc(2048 * 2);
  float* bcat = (float*)alloc(16 * 4);
  float* head_g = (float*)alloc((size_t)N * 8 * 4);
  float* head_r = (float*)alloc((size_t)N * 8 * 4);
  int* ctrs = (int*)alloc(4 * 4);

  int stripe = (((E + NB1 - 1) / NB1) + 255) & ~255;
  int nscan = NBUCK * NB1;
  int nbScan = (nscan + TPB - 1) / TPB;
  int nbNode = (N + 3) / 4;
  int ntiles = (N + 15) / 16;
  int nbC = (N * 32 + TPB - 1) / TPB;
  int PGRID = 2048;  // persistent grid: 256 CU x 8 blocks

  // CSR build — no global atomics
  hist1_k<<<NB1, 256, 0, stream>>>(ei, hist, E, stripe);
  scan1_k<<<nbScan, TPB, 0, stream>>>(hist, hist, chunk, nscan);
  scan2_k<<<1, 512, 0, stream>>>(chunk, nbScan);
  scan3_k<<<nbScan, TPB, 0, stream>>>(hist, chunk, nscan);
  scatter1_k<<<NB1, 256, 0, stream>>>(ei, hist, ebuf, E, stripe);
  build_k<<<NBKT, 256, 0, stream>>>(ebuf, hist, row_start, deg, invd, csr, N, E);

  // conversions + packing + counter zero (xh aliases ebuf: after build_k)
  prep_k<<<nbC, TPB, 0, stream>>>(x, xh, N * 32, W1l, W1r, W2l, W2r, W3l, W3r, wh,
                                  Wal, War, ba, Wsl, Wsr, bsx, Wel, Wer, be, Wcat,
                                  bcat, ctrs);

  // layer 1: x -> hA
  fused_sage_k<<<PGRID, TPB, 0, stream>>>(xh, wh + 0 * 16384, b1, csr, row_start, deg,
                                          invd, hA, nullptr, nullptr, nullptr, nullptr,
                                          ctrs + 0, ntiles, N, 0);
  // layer 2: hA -> hB
  fused_sage_k<<<PGRID, TPB, 0, stream>>>(hA, wh + 2 * 16384, b2, csr, row_start, deg,
                                          invd, hB, nullptr, nullptr, nullptr, nullptr,
                                          ctrs + 1, ntiles, N, 0);
  // layer 3 + heads: hB -> head_g[n,8], head_r[n,8]
  fused_sage_k<<<PGRID, TPB, 0, stream>>>(hB, wh + 4 * 16384, b3, csr, row_start, deg,
                                          invd, nullptr, Wcat, bcat, head_g, head_r,
                                          ctrs + 2, ntiles, N, 1);
  // final 8-dim neighbor aggregation + output
  agg8_k<<<nbNode, TPB, 0, stream>>>(head_g, head_r, csr, row_start, deg, invd,
                                     (float*)d_out, N);
}

// Round 8
// 681.384 us; speedup vs baseline: 1.6488x; 1.1259x over previous
//
#include <hip/hip_runtime.h>

#define TPB 256
#define NB1 256    // stripe blocks for edge passes
#define NBUCK 512  // coarse buckets (dst>>8); supports N <= 131072

using half4_t = __attribute__((ext_vector_type(4))) _Float16;
using half8_t = __attribute__((ext_vector_type(8))) _Float16;
using f32x4 = __attribute__((ext_vector_type(4))) float;

// ---------------- CSR build: atomic-free MSD counting sort ----------------

__global__ __launch_bounds__(256) void hist1_k(const int* __restrict__ ei,
                                               int* __restrict__ hist, int E, int stripe) {
  __shared__ int h[NBUCK];
  for (int i = threadIdx.x; i < NBUCK; i += 256) h[i] = 0;
  __syncthreads();
  int b0 = blockIdx.x * stripe;
  int b1 = min(b0 + stripe, E);
  for (int e = b0 + threadIdx.x; e < b1; e += 256) atomicAdd(&h[ei[E + e] >> 8], 1);
  __syncthreads();
  for (int i = threadIdx.x; i < NBUCK; i += 256) hist[i * NB1 + blockIdx.x] = h[i];
}

__global__ void scan1_k(const int* __restrict__ src, int* __restrict__ out,
                        int* __restrict__ chunk, int n) {
  __shared__ int sh[TPB];
  int i = blockIdx.x * TPB + threadIdx.x;
  int v = (i < n) ? src[i] : 0;
  sh[threadIdx.x] = v;
  __syncthreads();
  for (int off = 1; off < TPB; off <<= 1) {
    int t = (threadIdx.x >= off) ? sh[threadIdx.x - off] : 0;
    __syncthreads();
    sh[threadIdx.x] += t;
    __syncthreads();
  }
  if (i < n) out[i] = sh[threadIdx.x] - v;
  if (threadIdx.x == TPB - 1) chunk[blockIdx.x] = sh[TPB - 1];
}

__global__ void scan2_k(int* __restrict__ chunk, int nb) {
  __shared__ int sh[512];
  int v = (threadIdx.x < nb) ? chunk[threadIdx.x] : 0;
  sh[threadIdx.x] = v;
  __syncthreads();
  for (int off = 1; off < 512; off <<= 1) {
    int t = (threadIdx.x >= off) ? sh[threadIdx.x - off] : 0;
    __syncthreads();
    sh[threadIdx.x] += t;
    __syncthreads();
  }
  if (threadIdx.x < nb) chunk[threadIdx.x] = sh[threadIdx.x] - v;
}

__global__ void scan3_k(int* __restrict__ out, const int* __restrict__ chunk, int n) {
  int i = blockIdx.x * TPB + threadIdx.x;
  if (i < n) out[i] += chunk[blockIdx.x];
}

// pack: src (24 bits) | low8(dst) << 24
__global__ __launch_bounds__(256) void scatter1_k(const int* __restrict__ ei,
                                                  const int* __restrict__ base,
                                                  unsigned* __restrict__ ebuf, int E,
                                                  int stripe) {
  __shared__ int cur[NBUCK];
  for (int i = threadIdx.x; i < NBUCK; i += 256) cur[i] = base[i * NB1 + blockIdx.x];
  __syncthreads();
  int b0 = blockIdx.x * stripe;
  int b1 = min(b0 + stripe, E);
  for (int e = b0 + threadIdx.x; e < b1; e += 256) {
    int s = ei[e];
    int d = ei[E + e];
    int p = atomicAdd(&cur[d >> 8], 1);
    ebuf[p] = (unsigned)s | ((unsigned)(d & 255) << 24);
  }
}

__global__ __launch_bounds__(256) void build_k(const unsigned* __restrict__ ebuf,
                                               const int* __restrict__ base,
                                               int* __restrict__ row_start,
                                               int* __restrict__ deg,
                                               float* __restrict__ invd,
                                               int* __restrict__ csr, int N, int E) {
  __shared__ int h[256];
  __shared__ int excl[256];
  __shared__ int bse[2];
  int b = blockIdx.x;
  int t = threadIdx.x;
  if (t == 0) {
    bse[0] = base[b * NB1];
    bse[1] = (b + 1 < NBUCK) ? base[(b + 1) * NB1] : E;
  }
  h[t] = 0;
  __syncthreads();
  int bs = bse[0], be = bse[1];
  for (int e = bs + t; e < be; e += 256) atomicAdd(&h[ebuf[e] >> 24], 1);
  __syncthreads();
  int v = h[t];
  excl[t] = v;
  __syncthreads();
  for (int off = 1; off < 256; off <<= 1) {
    int tv = (t >= off) ? excl[t - off] : 0;
    __syncthreads();
    excl[t] += tv;
    __syncthreads();
  }
  int ex = excl[t] - v;
  int node = b * 256 + t;
  if (node < N) {
    row_start[node] = bs + ex;
    deg[node] = v;
    invd[node] = 1.0f / fmaxf((float)v, 1.0f);
  }
  h[t] = bs + ex;
  __syncthreads();
  for (int e = bs + t; e < be; e += 256) {
    unsigned p = ebuf[e];
    int pos = atomicAdd(&h[p >> 24], 1);
    csr[pos] = (int)(p & 0xFFFFFFu);
  }
}

// ---------------- prep: f2h(x) + weight converts + head pack ----------------

__global__ void prep_k(const float* __restrict__ x, _Float16* __restrict__ xh, int n4,
                       const float* __restrict__ w0, const float* __restrict__ w1,
                       const float* __restrict__ w2, const float* __restrict__ w3,
                       const float* __restrict__ w4, const float* __restrict__ w5,
                       _Float16* __restrict__ wh,
                       const float* __restrict__ Wal, const float* __restrict__ War,
                       const float* __restrict__ ba, const float* __restrict__ Wsl,
                       const float* __restrict__ Wsr, const float* __restrict__ bsx,
                       const float* __restrict__ Wel, const float* __restrict__ Wer,
                       const float* __restrict__ be, _Float16* __restrict__ Wcat,
                       float* __restrict__ bcat) {
  int t = blockIdx.x * TPB + threadIdx.x;
  if (t < n4) {
    float4 v = ((const float4*)x)[t];
    half4_t o;
    o.x = (_Float16)v.x; o.y = (_Float16)v.y; o.z = (_Float16)v.z; o.w = (_Float16)v.w;
    ((half4_t*)xh)[t] = o;
  }
  if (t < 6 * 4096) {
    int which = t >> 12, i = t & 4095;
    const float* src = which == 0 ? w0 : which == 1 ? w1 : which == 2 ? w2
                     : which == 3 ? w3 : which == 4 ? w4 : w5;
    float4 v = ((const float4*)src)[i];
    half4_t o;
    o.x = (_Float16)v.x; o.y = (_Float16)v.y; o.z = (_Float16)v.z; o.w = (_Float16)v.w;
    ((half4_t*)wh)[(size_t)which * 4096 + i] = o;
  }
  if (t < 2048) {
    float v = 0.f;
    if (t < 384) v = Wal[t];
    else if (t < 640) v = Wsl[t - 384];
    else if (t < 1024) v = Wel[t - 640];
    else if (t < 1408) v = War[t - 1024];
    else if (t < 1664) v = Wsr[t - 1408];
    else v = Wer[t - 1664];
    Wcat[t] = (_Float16)v;
  }
  if (t < 16) {
    float b = 0.f;
    if (t >= 8 && t < 11) b = ba[t - 8];
    else if (t >= 11 && t < 13) b = bsx[t - 11];
    else if (t >= 13) b = be[t - 13];
    bcat[t] = b;
  }
}

// ---------------- 128-dim mean aggregation (R1-verified: 103us, 76% occ) ----------------
// One wave per node. g=lane>>4 picks edge slot 0..3, l=lane&15 covers features
// l*8..l*8+7 (half8). 4 rows/instruction, 4 KB in flight, prefetched indices,
// branch-free masked tail.

__global__ __launch_bounds__(256) void agg128_k(const _Float16* __restrict__ hb,
                                                const int* __restrict__ csr,
                                                const int* __restrict__ row_start,
                                                const int* __restrict__ deg,
                                                const float* __restrict__ invd,
                                                _Float16* __restrict__ out, int n) {
  int node = (blockIdx.x << 2) + (threadIdx.x >> 6);
  if (node >= n) return;
  int lane = threadIdx.x & 63;
  int g = lane >> 4;  // edge slot 0..3
  int l = lane & 15;  // feature lane
  int s = row_start[node];
  int c = deg[node];
  const _Float16* base = hb + (l << 3);
  float a0 = 0.f, a1 = 0.f, a2 = 0.f, a3 = 0.f;
  float a4 = 0.f, a5 = 0.f, a6 = 0.f, a7 = 0.f;
  int j = 0;
  if (c >= 16) {
    int id[4];
#pragma unroll
    for (int p = 0; p < 4; ++p) id[p] = csr[s + 4 * p + g];
    while (true) {
      half8_t v[4];
#pragma unroll
      for (int p = 0; p < 4; ++p) v[p] = *(const half8_t*)&base[(size_t)id[p] * 128];
      j += 16;
      bool more = (j + 16 <= c);
      if (more) {
#pragma unroll
        for (int p = 0; p < 4; ++p) id[p] = csr[s + j + 4 * p + g];
      }
#pragma unroll
      for (int p = 0; p < 4; ++p) {
        a0 += (float)v[p][0]; a1 += (float)v[p][1];
        a2 += (float)v[p][2]; a3 += (float)v[p][3];
        a4 += (float)v[p][4]; a5 += (float)v[p][5];
        a6 += (float)v[p][6]; a7 += (float)v[p][7];
      }
      if (!more) break;
    }
  }
  if (j < c) {  // masked tail: 0..15 edges, all loads issued together
    int cm1 = c - 1;
#pragma unroll
    for (int p = 0; p < 4; ++p) {
      int e = j + 4 * p + g;
      float m = (e < c) ? 1.f : 0.f;
      int id = csr[s + min(e, cm1)];
      half8_t v = *(const half8_t*)&base[(size_t)id * 128];
      a0 = fmaf(m, (float)v[0], a0); a1 = fmaf(m, (float)v[1], a1);
      a2 = fmaf(m, (float)v[2], a2); a3 = fmaf(m, (float)v[3], a3);
      a4 = fmaf(m, (float)v[4], a4); a5 = fmaf(m, (float)v[5], a5);
      a6 = fmaf(m, (float)v[6], a6); a7 = fmaf(m, (float)v[7], a7);
    }
  }
  // reduce across the 4 edge slots (lanes l, l+16, l+32, l+48)
  a0 += __shfl_xor(a0, 16); a1 += __shfl_xor(a1, 16);
  a2 += __shfl_xor(a2, 16); a3 += __shfl_xor(a3, 16);
  a4 += __shfl_xor(a4, 16); a5 += __shfl_xor(a5, 16);
  a6 += __shfl_xor(a6, 16); a7 += __shfl_xor(a7, 16);
  a0 += __shfl_xor(a0, 32); a1 += __shfl_xor(a1, 32);
  a2 += __shfl_xor(a2, 32); a3 += __shfl_xor(a3, 32);
  a4 += __shfl_xor(a4, 32); a5 += __shfl_xor(a5, 32);
  a6 += __shfl_xor(a6, 32); a7 += __shfl_xor(a7, 32);
  if (g == 0) {
    float w = invd[node];
    half8_t r;
    r[0] = (_Float16)(a0 * w); r[1] = (_Float16)(a1 * w);
    r[2] = (_Float16)(a2 * w); r[3] = (_Float16)(a3 * w);
    r[4] = (_Float16)(a4 * w); r[5] = (_Float16)(a5 * w);
    r[6] = (_Float16)(a6 * w); r[7] = (_Float16)(a7 * w);
    *(half8_t*)&out[(size_t)node * 128 + (l << 3)] = r;
  }
}

// ---------------- dense dual GEMM: weights in LDS (XOR-swizzled), 64-row blocks ----------------
// outh = relu(Aagg@Wl^T + Ah@Wr^T + b). Block = 4 waves, 64 rows; each wave a
// 16-row strip x 128 cols (8 c-tiles of 16x16x32 f16 MFMA).
// Weight pair (2x128x128 fp16 = 64 KB) staged ONCE per block into LDS with a
// per-row XOR swizzle on the 16B k-chunk index (kc ^= row&7): the unswizzled
// [col][128] layout puts all 16 lanes of a bf read on one bank quad (16-way
// conflict); swizzled is ~2-way (free). Exactly 65536 B -> 2 blocks/CU.
// A-fragments (8 x half8 = 32 VGPR) prefetched from global before the K-loop;
// K-loop is pure LDS + MFMA. C layout: col=lane&15, row=quad*4+reg.

__global__ __launch_bounds__(256) void gemm2_k(
    const _Float16* __restrict__ Aagg, const _Float16* __restrict__ Ah,
    const _Float16* __restrict__ Wh,  // [2][128][128]: Wl then Wr
    const float* __restrict__ bias, _Float16* __restrict__ outh, int n) {
  __shared__ _Float16 Ws[32768];  // 64 KB: [row 0..255][k 0..127], kc swizzled
  int tid = threadIdx.x;
  int wave = tid >> 6;
  int lane = tid & 63;
  int g = lane >> 4;
  int l = lane & 15;
  int m0 = blockIdx.x * 64 + wave * 16;
  int arow = m0 + l;
  bool valid = arow < n;

  // prefetch A fragments (issue before staging so HBM latency hides under it)
  half8_t afA[4], afH[4];
  size_t abase = (size_t)arow * 128 + g * 8;
  if (valid) {
#pragma unroll
    for (int kb = 0; kb < 4; ++kb) afA[kb] = *(const half8_t*)&Aagg[abase + kb * 32];
#pragma unroll
    for (int kb = 0; kb < 4; ++kb) afH[kb] = *(const half8_t*)&Ah[abase + kb * 32];
  } else {
#pragma unroll
    for (int kb = 0; kb < 4; ++kb) {
#pragma unroll
      for (int jj = 0; jj < 8; ++jj) { afA[kb][jj] = (_Float16)0; afH[kb][jj] = (_Float16)0; }
    }
  }

  // stage weights: 256 rows x 16 chunks of 16 B; chunk kc stored at kc^(row&7)
#pragma unroll
  for (int it = 0; it < 16; ++it) {
    int ci = tid + it * 256;        // 0..4095
    int row = ci >> 4;              // 0..255 (s*128+col)
    int kc = ci & 15;
    float4 v = *(const float4*)&Wh[(size_t)row * 128 + kc * 8];
    *(float4*)&Ws[(size_t)row * 128 + ((kc ^ (row & 7)) * 8)] = v;
  }
  __syncthreads();

  f32x4 acc[8];
#pragma unroll
  for (int ct = 0; ct < 8; ++ct) acc[ct] = (f32x4){0.f, 0.f, 0.f, 0.f};

#pragma unroll
  for (int kb = 0; kb < 4; ++kb) {
#pragma unroll
    for (int ct = 0; ct < 8; ++ct) {
      int row = ct * 16 + l;  // Wl row (s=0)
      half8_t bf = *(const half8_t*)&Ws[(size_t)row * 128 + (((kb * 4 + g) ^ (l & 7)) * 8)];
      acc[ct] = __builtin_amdgcn_mfma_f32_16x16x32_f16(afA[kb], bf, acc[ct], 0, 0, 0);
    }
  }
#pragma unroll
  for (int kb = 0; kb < 4; ++kb) {
#pragma unroll
    for (int ct = 0; ct < 8; ++ct) {
      int row = 128 + ct * 16 + l;  // Wr row (s=1)
      half8_t bf = *(const half8_t*)&Ws[(size_t)row * 128 + (((kb * 4 + g) ^ (l & 7)) * 8)];
      acc[ct] = __builtin_amdgcn_mfma_f32_16x16x32_f16(afH[kb], bf, acc[ct], 0, 0, 0);
    }
  }

#pragma unroll
  for (int ct = 0; ct < 8; ++ct) {
    int col = ct * 16 + l;
    float bc = bias[col];
#pragma unroll
    for (int r = 0; r < 4; ++r) {
      int row = m0 + g * 4 + r;
      if (row < n) {
        float v = fmaxf(acc[ct][r] + bc, 0.f);
        outh[(size_t)row * 128 + col] = (_Float16)v;
      }
    }
  }
}

// ---------------- head GEMM: [n,16] = h3 @ Wcat^T + bcat, split outputs ----------------
// head_g[n][8] = gathered-head part (32 B rows for agg8), head_r[n][8] = root.

__global__ __launch_bounds__(256) void head_gemm_k(const _Float16* __restrict__ h,
                                                   const _Float16* __restrict__ Wcat,
                                                   const float* __restrict__ bcat,
                                                   float* __restrict__ head_g,
                                                   float* __restrict__ head_r, int n) {
  __shared__ _Float16 Ws[2048];  // 16 rows x 128, kc swizzled
  __shared__ float bs[16];
  int tid = threadIdx.x;
  {
    int row = tid >> 4, kc = tid & 15;  // 256 threads = 16x16 chunks exactly
    float4 v = *(const float4*)&Wcat[(size_t)row * 128 + kc * 8];
    *(float4*)&Ws[(size_t)row * 128 + ((kc ^ (row & 7)) * 8)] = v;
    if (tid < 16) bs[tid] = bcat[tid];
  }
  __syncthreads();
  int wave = tid >> 6;
  int lane = tid & 63;
  int g = lane >> 4;
  int l = lane & 15;
  int m0 = blockIdx.x * 64 + wave * 16;
  int arow = m0 + l;
  bool valid = arow < n;
  size_t abase = (size_t)arow * 128 + g * 8;
  f32x4 acc = (f32x4){0.f, 0.f, 0.f, 0.f};
#pragma unroll
  for (int kb = 0; kb < 4; ++kb) {
    half8_t af;
    if (valid) {
      af = *(const half8_t*)&h[abase + kb * 32];
    } else {
#pragma unroll
      for (int jj = 0; jj < 8; ++jj) af[jj] = (_Float16)0;
    }
    half8_t bf = *(const half8_t*)&Ws[(size_t)l * 128 + (((kb * 4 + g) ^ (l & 7)) * 8)];
    acc = __builtin_amdgcn_mfma_f32_16x16x32_f16(af, bf, acc, 0, 0, 0);
  }
  float bc = bs[l];
#pragma unroll
  for (int r = 0; r < 4; ++r) {
    int row = m0 + g * 4 + r;
    if (row < n) {
      float v = acc[r] + bc;
      if (l < 8) head_g[(size_t)row * 8 + l] = v;
      else head_r[(size_t)row * 8 + (l - 8)] = v;
    }
  }
}

// ---------------- 8-dim aggregation + output write ----------------
// out layout: age [n,3] @0, sex [n,2] @3n, eth [n,3] @5n
// head_g rows are 32 B: half the random-gather line traffic of [n,16].

__global__ void agg8_k(const float* __restrict__ head_g, const float* __restrict__ head_r,
                       const int* __restrict__ csr, const int* __restrict__ row_start,
                       const int* __restrict__ deg, const float* __restrict__ invd,
                       float* __restrict__ out, int n) {
  int node = (blockIdx.x << 2) + (threadIdx.x >> 6);
  if (node >= n) return;
  int lane = threadIdx.x & 63;
  int c2 = lane & 3;  // feature pair
  int g = lane >> 2;  // edge slot 0..15
  int s = row_start[node], cnt = deg[node];
  float ax = 0.f, ay = 0.f;
  int j = 0;
  for (; j + 32 <= cnt; j += 32) {
#pragma unroll
    for (int p = 0; p < 2; ++p) {
      int id = csr[s + j + 16 * p + g];
      float2 v = *(const float2*)&head_g[(size_t)id * 8 + 2 * c2];
      ax += v.x;
      ay += v.y;
    }
  }
  if (j < cnt) {
    int cm1 = cnt - 1;
#pragma unroll
    for (int p = 0; p < 2; ++p) {
      int e = j + 16 * p + g;
      float m = (e < cnt) ? 1.f : 0.f;
      int id = csr[s + min(e, cm1)];
      float2 v = *(const float2*)&head_g[(size_t)id * 8 + 2 * c2];
      ax = fmaf(m, v.x, ax);
      ay = fmaf(m, v.y, ay);
    }
  }
  ax += __shfl_xor(ax, 4);  ay += __shfl_xor(ay, 4);
  ax += __shfl_xor(ax, 8);  ay += __shfl_xor(ay, 8);
  ax += __shfl_xor(ax, 16); ay += __shfl_xor(ay, 16);
  ax += __shfl_xor(ax, 32); ay += __shfl_xor(ay, 32);
  if (g == 0) {
    float w = invd[node];
    float r0 = ax * w + head_r[(size_t)node * 8 + 2 * c2];
    float r1 = ay * w + head_r[(size_t)node * 8 + 2 * c2 + 1];
    float rr[2] = {r0, r1};
#pragma unroll
    for (int q = 0; q < 2; ++q) {
      int f = 2 * c2 + q;
      float r = rr[q];
      if (f < 3) out[(size_t)node * 3 + f] = r;
      else if (f < 5) out[(size_t)3 * n + (size_t)node * 2 + (f - 3)] = r;
      else out[(size_t)5 * n + (size_t)node * 3 + (f - 5)] = r;
    }
  }
}

// ---------------- launch ----------------

extern "C" void kernel_launch(void* const* d_in, const int* in_sizes, int n_in,
                              void* d_out, int out_size, void* d_ws, size_t ws_size,
                              hipStream_t stream) {
  const float* x = (const float*)d_in[0];
  const int* ei = (const int*)d_in[1];
  const float* W1l = (const float*)d_in[2];
  const float* W1r = (const float*)d_in[3];
  const float* b1 = (const float*)d_in[4];
  const float* W2l = (const float*)d_in[5];
  const float* W2r = (const float*)d_in[6];
  const float* b2 = (const float*)d_in[7];
  const float* W3l = (const float*)d_in[8];
  const float* W3r = (const float*)d_in[9];
  const float* b3 = (const float*)d_in[10];
  const float* Wal = (const float*)d_in[11];
  const float* War = (const float*)d_in[12];
  const float* ba = (const float*)d_in[13];
  const float* Wsl = (const float*)d_in[14];
  const float* Wsr = (const float*)d_in[15];
  const float* bsx = (const float*)d_in[16];
  const float* Wel = (const float*)d_in[17];
  const float* Wer = (const float*)d_in[18];
  const float* be = (const float*)d_in[19];

  int N = in_sizes[0] / 128;
  int E = in_sizes[1] / 2;
  int NBKT = (N + 255) >> 8;

  char* w = (char*)d_ws;
  auto alloc = [&](size_t b) {
    char* p = w;
    w += (b + 255) & ~(size_t)255;
    return p;
  };
  int* deg = (int*)alloc((size_t)N * 4);
  int* row_start = (int*)alloc((size_t)N * 4);
  float* invd = (float*)alloc((size_t)N * 4);
  int* hist = (int*)alloc((size_t)NBUCK * NB1 * 4);
  int* chunk = (int*)alloc(512 * 4);
  int* csr = (int*)alloc((size_t)E * 4);
  // xh (fp16 x, N*128*2 B) aliases ebuf (E*4 B): ebuf dead after build_k.
  size_t xh_bytes = (size_t)N * 128 * 2;
  size_t ebuf_bytes = (size_t)E * 4;
  char* region = (char*)alloc(xh_bytes > ebuf_bytes ? xh_bytes : ebuf_bytes);
  unsigned* ebuf = (unsigned*)region;
  _Float16* xh = (_Float16*)region;
  _Float16* aggh = (_Float16*)alloc((size_t)N * 128 * 2);
  _Float16* hA = (_Float16*)alloc((size_t)N * 128 * 2);
  _Float16* hB = (_Float16*)alloc((size_t)N * 128 * 2);
  _Float16* wh = (_Float16*)alloc((size_t)6 * 16384 * 2);
  _Float16* Wcat = (_Float16*)alloc(2048 * 2);
  float* bcat = (float*)alloc(16 * 4);
  float* head_g = (float*)alloc((size_t)N * 8 * 4);
  float* head_r = (float*)alloc((size_t)N * 8 * 4);

  int stripe = (((E + NB1 - 1) / NB1) + 255) & ~255;
  int nscan = NBUCK * NB1;
  int nbScan = (nscan + TPB - 1) / TPB;
  int nbNode = (N + 3) / 4;
  int nbM = (N + 63) / 64;
  int nbC = (N * 32 + TPB - 1) / TPB;

  // CSR build — no global atomics
  hist1_k<<<NB1, 256, 0, stream>>>(ei, hist, E, stripe);
  scan1_k<<<nbScan, TPB, 0, stream>>>(hist, hist, chunk, nscan);
  scan2_k<<<1, 512, 0, stream>>>(chunk, nbScan);
  scan3_k<<<nbScan, TPB, 0, stream>>>(hist, chunk, nscan);
  scatter1_k<<<NB1, 256, 0, stream>>>(ei, hist, ebuf, E, stripe);
  build_k<<<NBKT, 256, 0, stream>>>(ebuf, hist, row_start, deg, invd, csr, N, E);

  // conversions + packing (xh aliases ebuf: after build_k)
  prep_k<<<nbC, TPB, 0, stream>>>(x, xh, N * 32, W1l, W1r, W2l, W2r, W3l, W3r, wh,
                                  Wal, War, ba, Wsl, Wsr, bsx, Wel, Wer, be, Wcat, bcat);

  // layer 1: x -> hA
  agg128_k<<<nbNode, TPB, 0, stream>>>(xh, csr, row_start, deg, invd, aggh, N);
  gemm2_k<<<nbM, TPB, 0, stream>>>(aggh, xh, wh + 0 * 16384, b1, hA, N);
  // layer 2: hA -> hB
  agg128_k<<<nbNode, TPB, 0, stream>>>(hA, csr, row_start, deg, invd, aggh, N);
  gemm2_k<<<nbM, TPB, 0, stream>>>(aggh, hA, wh + 2 * 16384, b2, hB, N);
  // layer 3: hB -> hA
  agg128_k<<<nbNode, TPB, 0, stream>>>(hB, csr, row_start, deg, invd, aggh, N);
  gemm2_k<<<nbM, TPB, 0, stream>>>(aggh, hB, wh + 4 * 16384, b3, hA, N);
  // heads: transform to split 8+8 layout, then aggregate
  head_gemm_k<<<nbM, TPB, 0, stream>>>(hA, Wcat, bcat, head_g, head_r, N);
  agg8_k<<<nbNode, TPB, 0, stream>>>(head_g, head_r, csr, row_start, deg, invd,
                                     (float*)d_out, N);
}